// Round 1
// baseline (268.750 us; speedup 1.0000x reference)
//
#include <hip/hip_runtime.h>

// ---------------------------------------------------------------------------
// SimpleBiquadEQ: 10-band peaking-EQ cascade (IIR) over [32,2,262144] fp32.
//
// Exact chunk-parallel algorithm:
//   The 10-biquad cascade is linear with a 20-dim state s=(y1_k,y2_k) k=0..9.
//   Per chunk of L samples: s_end = A^L s_begin + t  (t = zero-state run with
//   true x drive). A depends only on batch coefs -> A^L shared by all chunks.
//   K1 computes t per chunk; an affine Kogge-Stone scan (precomputed matrix
//   powers A^(2^j)) resolves all chunk-boundary states exactly; K3 re-runs
//   each chunk from its true initial state and writes the output.
// ---------------------------------------------------------------------------

#define B_   32
#define C_   2
#define S_   262144
#define NB   10
#define SEQ  64          // B_*C_
#define LCH  256         // samples per chunk (2^8)
#define PCH  1024        // chunks per sequence
#define SUP  256         // super-chunks (4 chunks each) for the scan
#define NPOW 9           // stored matrix powers per batch: A^256, A^2^10..A^2^17

// ws layout (floats): coef [32][10][5] @0 ; powers [32][9][400] @1600 ;
//                     t [64][1024][20] @116800   -> total 1,427,520 f = 5.71 MB
#define WS_POW 1600
#define WS_T   116800

__global__ void coef_kernel(const float* __restrict__ freqs,
                            const float* __restrict__ gains,
                            const float* __restrict__ qs,
                            float* __restrict__ coef) {
  int idx = blockIdx.x * blockDim.x + threadIdx.x;
  if (idx >= B_ * NB) return;
  float f = freqs[idx], g = gains[idx], Q = qs[idx];
  float w0 = 6.28318530717958648f * f / 44100.0f;
  float sw = sinf(w0), cw = cosf(w0);
  float alpha = sw / (2.0f * Q);
  float A = expf(g * 0.05756462732485114f);   // 10^(g/40)
  float aA = alpha * A, adA = alpha / A;
  float inv = 1.0f / (1.0f + adA);
  float* o = coef + idx * 5;
  o[0] = (1.0f + aA) * inv;     // b0
  o[1] = -2.0f * cw * inv;      // b1
  o[2] = (1.0f - aA) * inv;     // b2
  o[3] = 2.0f * cw * inv;       // -a1 (pre-negated)
  o[4] = -(1.0f - adA) * inv;   // -a2 (pre-negated)
}

// Build the 20x20 one-step homogeneous matrix A and store A^(2^j) powers.
__global__ __launch_bounds__(256) void power_kernel(const float* __restrict__ coef,
                                                    float* __restrict__ powers) {
  __shared__ float bufA[400], bufB[400];
  int b = blockIdx.x, tid = threadIdx.x;
  const float* cf = coef + b * NB * 5;
  for (int e = tid; e < 400; e += 256) bufA[e] = 0.0f;
  __syncthreads();
  if (tid < 20) {
    int c = tid;           // column owned by this thread
    float rp = 0.0f;       // row p_{k-1}[c]
    for (int k = 0; k < NB; k++) {
      float b0 = cf[k*5+0], b1 = cf[k*5+1], b2 = cf[k*5+2];
      float na1 = cf[k*5+3], na2 = cf[k*5+4];
      float val = (k > 0) ? b0 * rp : 0.0f;
      if (k > 0) {
        if (c == 2*k-2) val += b1;
        if (c == 2*k-1) val += b2;
      }
      if (c == 2*k)   val += na1;
      if (c == 2*k+1) val += na2;
      bufA[2*k*20 + c] = val;          // row p_k
      rp = val;
      if (c == 2*k) bufA[(2*k+1)*20 + c] = 1.0f;  // row q_k = e_{p_k}
    }
  }
  __syncthreads();
  float* cur = bufA;
  float* nxt = bufB;
  float* pw = powers + (size_t)b * NPOW * 400;
  for (int j = 1; j <= 17; j++) {      // cur becomes A^(2^j)
    for (int e = tid; e < 400; e += 256) {
      int r = e / 20, c = e % 20;
      float acc = 0.0f;
      #pragma unroll
      for (int k = 0; k < 20; k++) acc = fmaf(cur[r*20+k], cur[k*20+c], acc);
      nxt[e] = acc;
    }
    __syncthreads();
    { float* t_ = cur; cur = nxt; nxt = t_; }
    if (j == 8)  for (int e = tid; e < 400; e += 256) pw[e] = cur[e];            // A^256
    if (j >= 10) for (int e = tid; e < 400; e += 256) pw[(j-9)*400 + e] = cur[e]; // A^2^j
  }
}

// K1 (WRITE_OUT=false): zero-state run -> chunk end-state t.
// K3 (WRITE_OUT=true) : exact run from scanned initial state -> output.
template <bool WRITE_OUT>
__global__ __launch_bounds__(256) void pass_kernel(const float* __restrict__ x,
                                                   const float* __restrict__ coef,
                                                   const float* __restrict__ sc,
                                                   float* __restrict__ tout,
                                                   float* __restrict__ out) {
  const int seq = blockIdx.y;                 // b*2 + c
  const int b = seq >> 1;
  const int chunk = blockIdx.x * blockDim.x + threadIdx.x;
  const float* cf = coef + b * NB * 5;        // block-uniform -> scalarized
  float b0[NB], b1[NB], b2[NB], na1[NB], na2[NB];
  #pragma unroll
  for (int k = 0; k < NB; k++) {
    b0[k] = cf[k*5+0]; b1[k] = cf[k*5+1]; b2[k] = cf[k*5+2];
    na1[k] = cf[k*5+3]; na2[k] = cf[k*5+4];
  }
  const float* xs = x + (size_t)seq * S_ + (size_t)chunk * LCH;
  float p[NB], q[NB];
  float x1 = 0.0f, x2 = 0.0f;
  if (chunk > 0) { x1 = xs[-1]; x2 = xs[-2]; }   // x drive history (known input)
  if (WRITE_OUT && chunk > 0) {
    const float* s0 = sc + ((size_t)seq * PCH + (chunk - 1)) * 20;
    #pragma unroll
    for (int k = 0; k < NB; k++) { p[k] = s0[2*k]; q[k] = s0[2*k+1]; }
  } else {
    #pragma unroll
    for (int k = 0; k < NB; k++) { p[k] = 0.0f; q[k] = 0.0f; }
  }
  const float4* xv = (const float4*)xs;
  float4* ov = nullptr;
  if (WRITE_OUT) ov = (float4*)(out + (size_t)seq * S_ + (size_t)chunk * LCH);
  #pragma unroll 1
  for (int n4 = 0; n4 < LCH / 4; n4++) {
    float4 xq = xv[n4];
    float xin[4] = {xq.x, xq.y, xq.z, xq.w};
    float o[4];
    #pragma unroll
    for (int j = 0; j < 4; j++) {
      float u = xin[j], u1 = x1, u2 = x2;
      x2 = x1; x1 = xin[j];
      #pragma unroll
      for (int k = 0; k < NB; k++) {
        float v = fmaf(b0[k], u,
                  fmaf(b1[k], u1,
                  fmaf(b2[k], u2,
                  fmaf(na1[k], p[k], na2[k] * q[k]))));
        u1 = p[k]; u2 = q[k];    // next band's input history = old outputs
        q[k] = p[k]; p[k] = v;   // shift this band
        u = v;
      }
      o[j] = u;
    }
    if (WRITE_OUT) ov[n4] = make_float4(o[0], o[1], o[2], o[3]);
  }
  if (!WRITE_OUT) {
    float* td = tout + ((size_t)seq * PCH + chunk) * 20;
    #pragma unroll
    for (int k = 0; k < NB; k++) { td[2*k] = p[k]; td[2*k+1] = q[k]; }
  }
}

__device__ __forceinline__ void mv20(float* __restrict__ o, const float* M,
                                     const float* v) {
  #pragma unroll
  for (int r = 0; r < 20; r++) {
    float acc = 0.0f;
    #pragma unroll
    for (int c = 0; c < 20; c++) acc = fmaf(M[r*20+c], v[c], acc);
    o[r] = acc;
  }
}

// Affine inclusive scan of chunk states, in place over t.
// Thread i owns chunks 4i..4i+3: Horner pre-combine with M=A^256, 8-step
// Kogge-Stone over 256 super-chunks with A^(2^(10+s)), then 3-step post-fill.
__global__ __launch_bounds__(256) void scan_kernel(float* __restrict__ t,
                                                   const float* __restrict__ powers) {
  __shared__ float h[SUP * 21];    // pad 21: stride coprime with 32 banks
  __shared__ float Msh[400];
  __shared__ float Ksh[400];
  const int seq = blockIdx.x, b = seq >> 1, i = threadIdx.x;
  const float* pw = powers + (size_t)b * NPOW * 400;
  for (int e = i; e < 400; e += 256) Msh[e] = pw[e];   // M = A^256
  __syncthreads();
  float* tb = t + (size_t)seq * PCH * 20;
  float u0[20], u1[20], u2[20], own[20], tmp[20];
  #pragma unroll
  for (int r = 0; r < 20; r++) u0[r] = tb[(4*i + 0)*20 + r];
  mv20(u1, Msh, u0);
  #pragma unroll
  for (int r = 0; r < 20; r++) u1[r] += tb[(4*i + 1)*20 + r];
  mv20(u2, Msh, u1);
  #pragma unroll
  for (int r = 0; r < 20; r++) u2[r] += tb[(4*i + 2)*20 + r];
  mv20(own, Msh, u2);
  #pragma unroll
  for (int r = 0; r < 20; r++) own[r] += tb[(4*i + 3)*20 + r];
  #pragma unroll
  for (int r = 0; r < 20; r++) h[i*21 + r] = own[r];
  for (int s = 0; s < 8; s++) {
    const int d = 1 << s;
    __syncthreads();   // h published; previous Ksh consumers done
    for (int e = i; e < 400; e += 256) Ksh[e] = pw[(1 + s)*400 + e];
    __syncthreads();   // Ksh ready
    float nb[20];
    if (i >= d) {
      #pragma unroll
      for (int r = 0; r < 20; r++) nb[r] = h[(i - d)*21 + r];
    }
    __syncthreads();   // all reads done before republish
    if (i >= d) {
      mv20(tmp, Ksh, nb);
      #pragma unroll
      for (int r = 0; r < 20; r++) { own[r] += tmp[r]; h[i*21 + r] = own[r]; }
    }
  }
  __syncthreads();
  float Pi[20];
  if (i > 0) {
    #pragma unroll
    for (int r = 0; r < 20; r++) Pi[r] = h[(i - 1)*21 + r];
  } else {
    #pragma unroll
    for (int r = 0; r < 20; r++) Pi[r] = 0.0f;
  }
  float w[20];
  mv20(w, Msh, Pi);     // state into chunk 4i
  #pragma unroll
  for (int r = 0; r < 20; r++) tb[(4*i + 0)*20 + r] = w[r] + u0[r];
  mv20(tmp, Msh, w);
  #pragma unroll
  for (int r = 0; r < 20; r++) tb[(4*i + 1)*20 + r] = tmp[r] + u1[r];
  mv20(w, Msh, tmp);
  #pragma unroll
  for (int r = 0; r < 20; r++) tb[(4*i + 2)*20 + r] = w[r] + u2[r];
  #pragma unroll
  for (int r = 0; r < 20; r++) tb[(4*i + 3)*20 + r] = own[r];
}

extern "C" void kernel_launch(void* const* d_in, const int* in_sizes, int n_in,
                              void* d_out, int out_size, void* d_ws, size_t ws_size,
                              hipStream_t stream) {
  const float* audio = (const float*)d_in[0];
  const float* freqs = (const float*)d_in[1];
  const float* gains = (const float*)d_in[2];
  const float* qs    = (const float*)d_in[3];
  float* out    = (float*)d_out;
  float* ws     = (float*)d_ws;
  float* coef   = ws;
  float* powers = ws + WS_POW;
  float* t      = ws + WS_T;

  hipLaunchKernelGGL(coef_kernel, dim3(5), dim3(64), 0, stream,
                     freqs, gains, qs, coef);
  hipLaunchKernelGGL(power_kernel, dim3(B_), dim3(256), 0, stream, coef, powers);
  hipLaunchKernelGGL((pass_kernel<false>), dim3(PCH / 256, SEQ), dim3(256), 0, stream,
                     audio, coef, (const float*)nullptr, t, (float*)nullptr);
  hipLaunchKernelGGL(scan_kernel, dim3(SEQ), dim3(256), 0, stream, t, powers);
  hipLaunchKernelGGL((pass_kernel<true>), dim3(PCH / 256, SEQ), dim3(256), 0, stream,
                     audio, coef, t, (float*)nullptr, out);
}